// Round 1
// baseline (584.345 us; speedup 1.0000x reference)
//
#include <hip/hip_runtime.h>

#define N_NODES 50000
#define HID 256
#define HEADS 8
#define HDIM 32
#define N_EDGES 800000

typedef __bf16 bf16x8 __attribute__((ext_vector_type(8)));
typedef float f32x4 __attribute__((ext_vector_type(4)));

__device__ __forceinline__ unsigned short f2bf(float f) {
    unsigned int b = __float_as_uint(f);
    unsigned int r = (b + 0x7FFFu + ((b >> 16) & 1u)) >> 16;
    return (unsigned short)r;
}
__device__ __forceinline__ float bf2f(unsigned short u) {
    return __uint_as_float(((unsigned int)u) << 16);
}

// ---------------- x fp32 -> bf16 ----------------
__global__ __launch_bounds__(256) void convert_x_kernel(
    const float* __restrict__ x, unsigned short* __restrict__ xb, int total8) {
    int t = blockIdx.x * 256 + threadIdx.x;
    if (t >= total8) return;
    const float4* p = reinterpret_cast<const float4*>(x) + (size_t)t * 2;
    float4 f0 = p[0], f1 = p[1];
    uint4 o;
    o.x = (unsigned)f2bf(f0.x) | ((unsigned)f2bf(f0.y) << 16);
    o.y = (unsigned)f2bf(f0.z) | ((unsigned)f2bf(f0.w) << 16);
    o.z = (unsigned)f2bf(f1.x) | ((unsigned)f2bf(f1.y) << 16);
    o.w = (unsigned)f2bf(f1.z) | ((unsigned)f2bf(f1.w) << 16);
    reinterpret_cast<uint4*>(xb)[t] = o;
}

// ---------------- pack fused weights into MFMA B-fragment order ----------------
// Wpack[((n_tile*8 + kk)*64 + lane)*8 + e] = W[k][n],
//   k = kk*32 + (lane>>4)*8 + e, n = n_tile*16 + (lane&15), fused n in [0,1024)
__global__ __launch_bounds__(256) void pack_w_kernel(
    const float* __restrict__ Wq, const float* __restrict__ Wk,
    const float* __restrict__ Wv, const float* __restrict__ Ws,
    const float* __restrict__ bq, const float* __restrict__ bk,
    const float* __restrict__ bv, const float* __restrict__ bs,
    unsigned short* __restrict__ wpack, float* __restrict__ biasF) {
    int t = blockIdx.x * 256 + threadIdx.x;  // 262144 total
    int e = t & 7, lane = (t >> 3) & 63, kk = (t >> 9) & 7, n_tile = t >> 12;
    int k = kk * 32 + (lane >> 4) * 8 + e;
    int n = n_tile * 16 + (lane & 15);
    const float* W[4] = {Wq, Wk, Wv, Ws};
    wpack[t] = f2bf(W[n >> 8][k * 256 + (n & 255)]);
    if (t < 1024) {
        const float* B[4] = {bq, bk, bv, bs};
        biasF[t] = B[t >> 8][t & 255];
    }
}

// ---------------- CSR build ----------------
__global__ __launch_bounds__(256) void hist_kernel(
    const int* __restrict__ dst, int* __restrict__ deg, int ne) {
    int e = blockIdx.x * 256 + threadIdx.x;
    if (e < ne) atomicAdd(&deg[dst[e]], 1);
}

__global__ __launch_bounds__(1024) void scan_kernel(
    const int* __restrict__ deg, int* __restrict__ row_ptr,
    int* __restrict__ fill, int n) {
    __shared__ int buf[1024];
    __shared__ int carry_s;
    int tid = threadIdx.x;
    if (tid == 0) carry_s = 0;
    __syncthreads();
    for (int base = 0; base < n; base += 1024) {
        int idx = base + tid;
        int v = (idx < n) ? deg[idx] : 0;
        buf[tid] = v;
        __syncthreads();
        for (int off = 1; off < 1024; off <<= 1) {
            int t = (tid >= off) ? buf[tid - off] : 0;
            __syncthreads();
            buf[tid] += t;
            __syncthreads();
        }
        int carry = carry_s;
        int excl = carry + buf[tid] - v;
        if (idx < n) { row_ptr[idx] = excl; fill[idx] = excl; }
        __syncthreads();
        if (tid == 1023) carry_s = carry + buf[1023];
        __syncthreads();
    }
    if (tid == 0) row_ptr[n] = carry_s;
}

__global__ __launch_bounds__(256) void scatter_kernel(
    const int* __restrict__ src, const int* __restrict__ dst,
    int* __restrict__ fill, int* __restrict__ csr_src, int ne) {
    int e = blockIdx.x * 256 + threadIdx.x;
    if (e < ne) {
        int pos = atomicAdd(&fill[dst[e]], 1);
        csr_src[pos] = src[e];
    }
}

// ---------------- fused QKVS GEMM (bf16 MFMA, no LDS) ----------------
// block = 256 thr (4 waves stacked in M), tile 128(M) x 64(N), K = 256
__global__ __launch_bounds__(256) void gemm_kernel(
    const unsigned short* __restrict__ xb,     // [N][256] bf16
    const unsigned short* __restrict__ wpack,  // packed B
    const float* __restrict__ biasF,           // [1024]
    unsigned short* __restrict__ qkvs,         // [N][1024] bf16
    int n_nodes) {
    int lane = threadIdx.x & 63;
    int wv = threadIdx.x >> 6;
    int row_w = blockIdx.x * 128 + wv * 32;
    int n0 = blockIdx.y * 64;

    f32x4 acc[2][4];
#pragma unroll
    for (int mi = 0; mi < 2; ++mi)
#pragma unroll
        for (int ni = 0; ni < 4; ++ni) {
            f32x4 z = {0.f, 0.f, 0.f, 0.f};
            acc[mi][ni] = z;
        }

    int arow0 = min(row_w + (lane & 15), n_nodes - 1);
    int arow1 = min(row_w + 16 + (lane & 15), n_nodes - 1);
    int acol = (lane >> 4) * 8;
    const uint4* bbase = reinterpret_cast<const uint4*>(wpack);
    int ntile0 = n0 >> 4;

#pragma unroll
    for (int kk = 0; kk < 8; ++kk) {
        bf16x8 a[2], b[4];
        {
            uint4 u0 = *reinterpret_cast<const uint4*>(xb + (size_t)arow0 * 256 + kk * 32 + acol);
            uint4 u1 = *reinterpret_cast<const uint4*>(xb + (size_t)arow1 * 256 + kk * 32 + acol);
            a[0] = __builtin_bit_cast(bf16x8, u0);
            a[1] = __builtin_bit_cast(bf16x8, u1);
        }
#pragma unroll
        for (int ni = 0; ni < 4; ++ni) {
            uint4 u = bbase[((size_t)(ntile0 + ni) * 8 + kk) * 64 + lane];
            b[ni] = __builtin_bit_cast(bf16x8, u);
        }
#pragma unroll
        for (int mi = 0; mi < 2; ++mi)
#pragma unroll
            for (int ni = 0; ni < 4; ++ni)
                acc[mi][ni] = __builtin_amdgcn_mfma_f32_16x16x32_bf16(a[mi], b[ni], acc[mi][ni], 0, 0, 0);
    }

#pragma unroll
    for (int mi = 0; mi < 2; ++mi) {
        int rbase = row_w + mi * 16 + (lane >> 4) * 4;
#pragma unroll
        for (int ni = 0; ni < 4; ++ni) {
            int col = n0 + ni * 16 + (lane & 15);
            float bias = biasF[col];
#pragma unroll
            for (int r = 0; r < 4; ++r) {
                int row = rbase + r;
                if (row < n_nodes)
                    qkvs[(size_t)row * 1024 + col] = f2bf(acc[mi][ni][r] + bias);
            }
        }
    }
}

// ---------------- fused edge aggregation + epilogue ----------------
// 1 block (256 thr) per dst node; thread c = h*32+d channel
__global__ __launch_bounds__(256) void edge_agg_kernel(
    const int* __restrict__ row_ptr, const int* __restrict__ csr_src,
    const unsigned short* __restrict__ qkvs, const float* __restrict__ x,
    const float* __restrict__ gamma, const float* __restrict__ beta,
    float* __restrict__ out) {
    int i = blockIdx.x;
    int c = threadIdx.x;
    int lane = c & 63;
    int wave = c >> 6;

    const float inv_sqrt_d = 0.17677669529663687f;  // 1/sqrt(32)
    float qc = bf2f(qkvs[(size_t)i * 1024 + c]) * inv_sqrt_d;

    int e0 = row_ptr[i], e1 = row_ptr[i + 1];
    float acc = 0.f, denom = 0.f;
    int j_next = (e0 < e1) ? csr_src[e0] : 0;
    for (int e = e0; e < e1; ++e) {
        int j = j_next;
        if (e + 1 < e1) j_next = csr_src[e + 1];
        float kc = bf2f(qkvs[(size_t)j * 1024 + 256 + c]);
        float vc = bf2f(qkvs[(size_t)j * 1024 + 512 + c]);
        float s = qc * kc;
        s += __shfl_xor(s, 1);
        s += __shfl_xor(s, 2);
        s += __shfl_xor(s, 4);
        s += __shfl_xor(s, 8);
        s += __shfl_xor(s, 16);   // logits tiny (|s|<~1): softmax shift-invariant, no max needed
        float w = expf(s);
        denom += w;
        acc = fmaf(w, vc, acc);
    }
    float agg = (denom > 0.f) ? (acc / denom) : 0.f;

    float pre = agg + bf2f(qkvs[(size_t)i * 1024 + 768 + c]);
    float gel = 0.5f * pre * (1.f + erff(pre * 0.70710678118654752f));
    float y = x[(size_t)i * 256 + c] + gel;

    // LayerNorm over 256 channels
    float s1 = y, s2 = y * y;
#pragma unroll
    for (int m = 1; m <= 32; m <<= 1) {
        s1 += __shfl_xor(s1, m);
        s2 += __shfl_xor(s2, m);
    }
    __shared__ float red[8];
    if (lane == 0) { red[wave] = s1; red[4 + wave] = s2; }
    __syncthreads();
    float sum = red[0] + red[1] + red[2] + red[3];
    float ssq = red[4] + red[5] + red[6] + red[7];
    float mu = sum * (1.f / 256.f);
    float var = ssq * (1.f / 256.f) - mu * mu;
    float rstd = rsqrtf(var + 1e-5f);
    out[(size_t)i * 256 + c] = (y - mu) * rstd * gamma[c] + beta[c];
}

extern "C" void kernel_launch(void* const* d_in, const int* in_sizes, int n_in,
                              void* d_out, int out_size, void* d_ws, size_t ws_size,
                              hipStream_t stream) {
    const float* x    = (const float*)d_in[0];
    const int*   ei   = (const int*)d_in[1];
    const float* Wq   = (const float*)d_in[2];
    const float* bq   = (const float*)d_in[3];
    const float* Wk   = (const float*)d_in[4];
    const float* bk   = (const float*)d_in[5];
    const float* Wv   = (const float*)d_in[6];
    const float* bv   = (const float*)d_in[7];
    const float* Wsk  = (const float*)d_in[8];
    const float* bsk  = (const float*)d_in[9];
    const float* gamma = (const float*)d_in[10];
    const float* beta  = (const float*)d_in[11];
    const int* src = ei;
    const int* dst = ei + N_EDGES;

    char* ws = (char*)d_ws;
    size_t off = 0;
    auto alloc = [&](size_t bytes) -> void* {
        void* p = ws + off;
        off += (bytes + 255) & ~(size_t)255;
        return p;
    };
    unsigned short* xb     = (unsigned short*)alloc((size_t)N_NODES * 256 * 2);
    unsigned short* qkvs   = (unsigned short*)alloc((size_t)N_NODES * 1024 * 2);
    unsigned short* wpack  = (unsigned short*)alloc(262144 * 2);
    float*          biasF  = (float*)alloc(1024 * 4);
    int*            deg    = (int*)alloc((size_t)N_NODES * 4);
    int*            rowp   = (int*)alloc((size_t)(N_NODES + 1) * 4);
    int*            fill   = (int*)alloc((size_t)N_NODES * 4);
    int*            csr    = (int*)alloc((size_t)N_EDGES * 4);
    (void)ws_size;

    hipMemsetAsync(deg, 0, (size_t)N_NODES * 4, stream);
    convert_x_kernel<<<(N_NODES * 256 / 8 + 255) / 256, 256, 0, stream>>>(
        x, xb, N_NODES * 256 / 8);
    pack_w_kernel<<<1024, 256, 0, stream>>>(Wq, Wk, Wv, Wsk, bq, bk, bv, bsk, wpack, biasF);
    hist_kernel<<<(N_EDGES + 255) / 256, 256, 0, stream>>>(dst, deg, N_EDGES);
    scan_kernel<<<1, 1024, 0, stream>>>(deg, rowp, fill, N_NODES);
    scatter_kernel<<<(N_EDGES + 255) / 256, 256, 0, stream>>>(src, dst, fill, csr, N_EDGES);
    gemm_kernel<<<dim3((N_NODES + 127) / 128, 16), 256, 0, stream>>>(xb, wpack, biasF, qkvs, N_NODES);
    edge_agg_kernel<<<N_NODES, 256, 0, stream>>>(rowp, csr, qkvs, x, gamma, beta, (float*)d_out);
}

// Round 2
// 458.888 us; speedup vs baseline: 1.2734x; 1.2734x over previous
//
#include <hip/hip_runtime.h>

#define N_NODES 50000
#define HID 256
#define HEADS 8
#define HDIM 32
#define N_EDGES 800000

typedef __bf16 bf16x8 __attribute__((ext_vector_type(8)));
typedef float f32x4 __attribute__((ext_vector_type(4)));

__device__ __forceinline__ unsigned short f2bf(float f) {
    unsigned int b = __float_as_uint(f);
    unsigned int r = (b + 0x7FFFu + ((b >> 16) & 1u)) >> 16;
    return (unsigned short)r;
}
__device__ __forceinline__ float bf2f(unsigned short u) {
    return __uint_as_float(((unsigned int)u) << 16);
}

// ---------------- x fp32 -> bf16 ----------------
__global__ __launch_bounds__(256) void convert_x_kernel(
    const float* __restrict__ x, unsigned short* __restrict__ xb, int total8) {
    int t = blockIdx.x * 256 + threadIdx.x;
    if (t >= total8) return;
    const float4* p = reinterpret_cast<const float4*>(x) + (size_t)t * 2;
    float4 f0 = p[0], f1 = p[1];
    uint4 o;
    o.x = (unsigned)f2bf(f0.x) | ((unsigned)f2bf(f0.y) << 16);
    o.y = (unsigned)f2bf(f0.z) | ((unsigned)f2bf(f0.w) << 16);
    o.z = (unsigned)f2bf(f1.x) | ((unsigned)f2bf(f1.y) << 16);
    o.w = (unsigned)f2bf(f1.z) | ((unsigned)f2bf(f1.w) << 16);
    reinterpret_cast<uint4*>(xb)[t] = o;
}

// ---------------- pack fused weights into MFMA B-fragment order ----------------
// Output column position p in [0,1024):
//   p<256        : Q, col p
//   256<=p<768   : c=(p-256)>>1 ; even -> K col c, odd -> V col c  (k/v interleaved!)
//   p>=768       : skip, col p-768
// Wpack[((n_tile*8 + kk)*64 + lane)*8 + e] = W[k][p],
//   k = kk*32 + (lane>>4)*8 + e, p = n_tile*16 + (lane&15)
__global__ __launch_bounds__(256) void pack_w_kernel(
    const float* __restrict__ Wq, const float* __restrict__ Wk,
    const float* __restrict__ Wv, const float* __restrict__ Ws,
    const float* __restrict__ bq, const float* __restrict__ bk,
    const float* __restrict__ bv, const float* __restrict__ bs,
    unsigned short* __restrict__ wpack, float* __restrict__ biasF) {
    int t = blockIdx.x * 256 + threadIdx.x;  // 262144 total
    int e = t & 7, lane = (t >> 3) & 63, kk = (t >> 9) & 7, n_tile = t >> 12;
    int k = kk * 32 + (lane >> 4) * 8 + e;
    int p = n_tile * 16 + (lane & 15);
    const float* W[4] = {Wq, Wk, Wv, Ws};
    int mat, col;
    if (p < 256) { mat = 0; col = p; }
    else if (p < 768) { col = (p - 256) >> 1; mat = ((p - 256) & 1) ? 2 : 1; }
    else { mat = 3; col = p - 768; }
    wpack[t] = f2bf(W[mat][k * 256 + col]);
    if (t < 1024) {
        const float* B[4] = {bq, bk, bv, bs};
        int p2 = t, mat2, col2;
        if (p2 < 256) { mat2 = 0; col2 = p2; }
        else if (p2 < 768) { col2 = (p2 - 256) >> 1; mat2 = ((p2 - 256) & 1) ? 2 : 1; }
        else { mat2 = 3; col2 = p2 - 768; }
        biasF[t] = B[mat2][col2];
    }
}

// ---------------- CSR build ----------------
__global__ __launch_bounds__(256) void hist_kernel(
    const int* __restrict__ dst, int* __restrict__ deg, int ne) {
    int e = blockIdx.x * 256 + threadIdx.x;
    if (e < ne) atomicAdd(&deg[dst[e]], 1);
}

// chunked scan: thread sums 49 elems, shfl-scan across 1024, second pass writes
__global__ __launch_bounds__(1024) void scan_kernel(
    const int* __restrict__ deg, int* __restrict__ row_ptr,
    int* __restrict__ fill, int n) {
    const int CH = 49;  // 1024*49 = 50176 >= 50000
    int tid = threadIdx.x;
    int lane = tid & 63, wv = tid >> 6;
    int start = tid * CH;
    int sum = 0;
    for (int k = 0; k < CH; ++k) {
        int idx = start + k;
        if (idx < n) sum += deg[idx];
    }
    // inclusive wave scan
    int inc = sum;
    for (int off = 1; off < 64; off <<= 1) {
        int t2 = __shfl_up(inc, off);
        if (lane >= off) inc += t2;
    }
    __shared__ int sWave[16];
    if (lane == 63) sWave[wv] = inc;
    __syncthreads();
    __shared__ int sWoff[16];
    if (tid < 16) {
        int v = sWave[tid], in2 = v;
        for (int off = 1; off < 16; off <<= 1) {
            int t2 = __shfl_up(in2, off);
            if (tid >= off) in2 += t2;
        }
        sWoff[tid] = in2 - v;  // exclusive
    }
    __syncthreads();
    int excl = sWoff[wv] + inc - sum;
    int running = excl;
    for (int k = 0; k < CH; ++k) {
        int idx = start + k;
        if (idx < n) {
            row_ptr[idx] = running;
            fill[idx] = running;
            running += deg[idx];
        }
    }
    if (tid == 1023) row_ptr[n] = excl;  // start=50127>=n, so excl == total
}

__global__ __launch_bounds__(256) void scatter_kernel(
    const int* __restrict__ src, const int* __restrict__ dst,
    int* __restrict__ fill, int* __restrict__ csr_src, int ne) {
    int e = blockIdx.x * 256 + threadIdx.x;
    if (e < ne) {
        int pos = atomicAdd(&fill[dst[e]], 1);
        csr_src[pos] = src[e];
    }
}

// ---------------- fused QKVS GEMM (bf16 MFMA, no LDS) ----------------
// 1D grid 6256 = 391 Mtiles x 16 Ntiles; XCD-chunked so each XCD owns a
// contiguous M-range (A working set 3.2MB < 4MB L2 per XCD).
__global__ __launch_bounds__(256) void gemm_kernel(
    const unsigned short* __restrict__ xb,     // [N][256] bf16
    const unsigned short* __restrict__ wpack,  // packed B
    const float* __restrict__ biasF,           // [1024]
    unsigned short* __restrict__ qkvs,         // [N][1024] bf16
    int n_nodes) {
    int bid = blockIdx.x;                      // 6256 = 8 * 782
    int work = (bid & 7) * 782 + (bid >> 3);
    int mt = work >> 4;
    int nt = work & 15;
    int lane = threadIdx.x & 63;
    int wv = threadIdx.x >> 6;
    int row_w = mt * 128 + wv * 32;
    int n0 = nt * 64;

    f32x4 acc[2][4];
#pragma unroll
    for (int mi = 0; mi < 2; ++mi)
#pragma unroll
        for (int ni = 0; ni < 4; ++ni) {
            f32x4 z = {0.f, 0.f, 0.f, 0.f};
            acc[mi][ni] = z;
        }

    int arow0 = min(row_w + (lane & 15), n_nodes - 1);
    int arow1 = min(row_w + 16 + (lane & 15), n_nodes - 1);
    int acol = (lane >> 4) * 8;
    const uint4* bbase = reinterpret_cast<const uint4*>(wpack);
    int ntile0 = n0 >> 4;

#pragma unroll
    for (int kk = 0; kk < 8; ++kk) {
        bf16x8 a[2], b[4];
        {
            uint4 u0 = *reinterpret_cast<const uint4*>(xb + (size_t)arow0 * 256 + kk * 32 + acol);
            uint4 u1 = *reinterpret_cast<const uint4*>(xb + (size_t)arow1 * 256 + kk * 32 + acol);
            a[0] = __builtin_bit_cast(bf16x8, u0);
            a[1] = __builtin_bit_cast(bf16x8, u1);
        }
#pragma unroll
        for (int ni = 0; ni < 4; ++ni) {
            uint4 u = bbase[((size_t)(ntile0 + ni) * 8 + kk) * 64 + lane];
            b[ni] = __builtin_bit_cast(bf16x8, u);
        }
#pragma unroll
        for (int mi = 0; mi < 2; ++mi)
#pragma unroll
            for (int ni = 0; ni < 4; ++ni)
                acc[mi][ni] = __builtin_amdgcn_mfma_f32_16x16x32_bf16(a[mi], b[ni], acc[mi][ni], 0, 0, 0);
    }

#pragma unroll
    for (int mi = 0; mi < 2; ++mi) {
        int rbase = row_w + mi * 16 + (lane >> 4) * 4;
#pragma unroll
        for (int ni = 0; ni < 4; ++ni) {
            int col = n0 + ni * 16 + (lane & 15);
            float bias = biasF[col];
#pragma unroll
            for (int r = 0; r < 4; ++r) {
                int row = rbase + r;
                if (row < n_nodes)
                    qkvs[(size_t)row * 1024 + col] = f2bf(acc[mi][ni][r] + bias);
            }
        }
    }
}

// ---------------- fused edge aggregation + epilogue ----------------
// 1 block per dst node; 4 waves; 1 wave = 1 edge (64 lanes x 4 channels).
// qkvs row layout: q[0:256], kv-interleaved[256:768], skip[768:1024]
__global__ __launch_bounds__(256) void edge_agg_kernel(
    const int* __restrict__ row_ptr, const int* __restrict__ csr_src,
    const unsigned short* __restrict__ qkvs, const float* __restrict__ x,
    const float* __restrict__ gamma, const float* __restrict__ beta,
    float* __restrict__ out) {
    int i = blockIdx.x;
    int t = threadIdx.x;
    int slot = t >> 6;   // wave id = edge slot
    int lane = t & 63;
    int h = lane >> 3;   // head
    int hd = lane & 7;   // 4-channel group in head
    int c0 = h * 32 + hd * 4;

    // q[c0..c0+3], pre-scaled by log2(e)/sqrt(32) so w = exp2(dot)
    const float SC = 0.17677669529663687f * 1.4426950408889634f;
    uint2 qu = *reinterpret_cast<const uint2*>(qkvs + (size_t)i * 1024 + c0);
    float q0 = __uint_as_float(qu.x << 16) * SC;
    float q1 = __uint_as_float(qu.x & 0xffff0000u) * SC;
    float q2 = __uint_as_float(qu.y << 16) * SC;
    float q3 = __uint_as_float(qu.y & 0xffff0000u) * SC;

    int e0 = row_ptr[i], e1 = row_ptr[i + 1];
    float a0 = 0.f, a1 = 0.f, a2 = 0.f, a3 = 0.f, den = 0.f;
    int e = e0 + slot;
    int j = (e < e1) ? csr_src[e] : 0;
    for (; e < e1; e += 4) {
        int jn = (e + 4 < e1) ? csr_src[e + 4] : 0;
        uint4 u = *reinterpret_cast<const uint4*>(qkvs + (size_t)j * 1024 + 256 + 2 * c0);
        float k0 = __uint_as_float(u.x << 16), v0 = __uint_as_float(u.x & 0xffff0000u);
        float k1 = __uint_as_float(u.y << 16), v1 = __uint_as_float(u.y & 0xffff0000u);
        float k2 = __uint_as_float(u.z << 16), v2 = __uint_as_float(u.z & 0xffff0000u);
        float k3 = __uint_as_float(u.w << 16), v3 = __uint_as_float(u.w & 0xffff0000u);
        float s = q0 * k0;
        s = fmaf(q1, k1, s);
        s = fmaf(q2, k2, s);
        s = fmaf(q3, k3, s);
        s += __shfl_xor(s, 1);
        s += __shfl_xor(s, 2);
        s += __shfl_xor(s, 4);   // logits tiny: softmax shift-invariant, no max needed
        float w = exp2f(s);
        den += w;
        a0 = fmaf(w, v0, a0);
        a1 = fmaf(w, v1, a1);
        a2 = fmaf(w, v2, a2);
        a3 = fmaf(w, v3, a3);
        j = jn;
    }

    __shared__ float sAcc[4][64][4];
    __shared__ float sDen[4][8];
    sAcc[slot][lane][0] = a0;
    sAcc[slot][lane][1] = a1;
    sAcc[slot][lane][2] = a2;
    sAcc[slot][lane][3] = a3;
    if (hd == 0) sDen[slot][h] = den;
    __syncthreads();

    // epilogue: thread t owns channel c = t
    int c = t;
    int hh = c >> 5, dd = c & 31;
    int l2 = hh * 8 + (dd >> 2), ee = dd & 3;
    float acc = sAcc[0][l2][ee] + sAcc[1][l2][ee] + sAcc[2][l2][ee] + sAcc[3][l2][ee];
    float d = sDen[0][hh] + sDen[1][hh] + sDen[2][hh] + sDen[3][hh];
    float agg = (d > 0.f) ? acc / d : 0.f;

    float pre = agg + bf2f(qkvs[(size_t)i * 1024 + 768 + c]);
    float gel = 0.5f * pre * (1.f + erff(pre * 0.70710678118654752f));
    float y = x[(size_t)i * 256 + c] + gel;

    // LayerNorm over 256 channels
    float s1 = y, s2 = y * y;
#pragma unroll
    for (int m = 1; m <= 32; m <<= 1) {
        s1 += __shfl_xor(s1, m);
        s2 += __shfl_xor(s2, m);
    }
    __shared__ float red[8];
    int wave = t >> 6, ln = t & 63;
    if (ln == 0) { red[wave] = s1; red[4 + wave] = s2; }
    __syncthreads();
    float sum = red[0] + red[1] + red[2] + red[3];
    float ssq = red[4] + red[5] + red[6] + red[7];
    float mu = sum * (1.f / 256.f);
    float var = ssq * (1.f / 256.f) - mu * mu;
    float rstd = rsqrtf(var + 1e-5f);
    out[(size_t)i * 256 + c] = (y - mu) * rstd * gamma[c] + beta[c];
}

extern "C" void kernel_launch(void* const* d_in, const int* in_sizes, int n_in,
                              void* d_out, int out_size, void* d_ws, size_t ws_size,
                              hipStream_t stream) {
    const float* x    = (const float*)d_in[0];
    const int*   ei   = (const int*)d_in[1];
    const float* Wq   = (const float*)d_in[2];
    const float* bq   = (const float*)d_in[3];
    const float* Wk   = (const float*)d_in[4];
    const float* bk   = (const float*)d_in[5];
    const float* Wv   = (const float*)d_in[6];
    const float* bv   = (const float*)d_in[7];
    const float* Wsk  = (const float*)d_in[8];
    const float* bsk  = (const float*)d_in[9];
    const float* gamma = (const float*)d_in[10];
    const float* beta  = (const float*)d_in[11];
    const int* src = ei;
    const int* dst = ei + N_EDGES;

    char* ws = (char*)d_ws;
    size_t off = 0;
    auto alloc = [&](size_t bytes) -> void* {
        void* p = ws + off;
        off += (bytes + 255) & ~(size_t)255;
        return p;
    };
    unsigned short* xb     = (unsigned short*)alloc((size_t)N_NODES * 256 * 2);
    unsigned short* qkvs   = (unsigned short*)alloc((size_t)N_NODES * 1024 * 2);
    unsigned short* wpack  = (unsigned short*)alloc(262144 * 2);
    float*          biasF  = (float*)alloc(1024 * 4);
    int*            deg    = (int*)alloc((size_t)N_NODES * 4);
    int*            rowp   = (int*)alloc((size_t)(N_NODES + 1) * 4);
    int*            fill   = (int*)alloc((size_t)N_NODES * 4);
    int*            csr    = (int*)alloc((size_t)N_EDGES * 4);
    (void)ws_size;

    hipMemsetAsync(deg, 0, (size_t)N_NODES * 4, stream);
    convert_x_kernel<<<(N_NODES * 256 / 8 + 255) / 256, 256, 0, stream>>>(
        x, xb, N_NODES * 256 / 8);
    pack_w_kernel<<<1024, 256, 0, stream>>>(Wq, Wk, Wv, Wsk, bq, bk, bv, bsk, wpack, biasF);
    hist_kernel<<<(N_EDGES + 255) / 256, 256, 0, stream>>>(dst, deg, N_EDGES);
    scan_kernel<<<1, 1024, 0, stream>>>(deg, rowp, fill, N_NODES);
    scatter_kernel<<<(N_EDGES + 255) / 256, 256, 0, stream>>>(src, dst, fill, csr, N_EDGES);
    gemm_kernel<<<6256, 256, 0, stream>>>(xb, wpack, biasF, qkvs, N_NODES);
    edge_agg_kernel<<<N_NODES, 256, 0, stream>>>(rowp, csr, qkvs, x, gamma, beta, (float*)d_out);
}

// Round 3
// 333.336 us; speedup vs baseline: 1.7530x; 1.3767x over previous
//
#include <hip/hip_runtime.h>

#define N_NODES 50000
#define HID 256
#define HEADS 8
#define HDIM 32
#define N_EDGES 800000

typedef __bf16 bf16x8 __attribute__((ext_vector_type(8)));
typedef float f32x4 __attribute__((ext_vector_type(4)));
typedef float f32x2 __attribute__((ext_vector_type(2)));

__device__ __forceinline__ unsigned short f2bf(float f) {
    unsigned int b = __float_as_uint(f);
    unsigned int r = (b + 0x7FFFu + ((b >> 16) & 1u)) >> 16;
    return (unsigned short)r;
}
__device__ __forceinline__ float bf2f(unsigned short u) {
    return __uint_as_float(((unsigned int)u) << 16);
}

// ---------------- x fp32 -> bf16 ----------------
__global__ __launch_bounds__(256) void convert_x_kernel(
    const float* __restrict__ x, unsigned short* __restrict__ xb, int total8) {
    int t = blockIdx.x * 256 + threadIdx.x;
    if (t >= total8) return;
    const float4* p = reinterpret_cast<const float4*>(x) + (size_t)t * 2;
    float4 f0 = p[0], f1 = p[1];
    uint4 o;
    o.x = (unsigned)f2bf(f0.x) | ((unsigned)f2bf(f0.y) << 16);
    o.y = (unsigned)f2bf(f0.z) | ((unsigned)f2bf(f0.w) << 16);
    o.z = (unsigned)f2bf(f1.x) | ((unsigned)f2bf(f1.y) << 16);
    o.w = (unsigned)f2bf(f1.z) | ((unsigned)f2bf(f1.w) << 16);
    reinterpret_cast<uint4*>(xb)[t] = o;
}

// ---------------- pack fused weights into MFMA B-fragment order ----------------
// Fused column p in [0,1024):
//   p<256      : Q col p                       (bf16 output)
//   256<=p<768 : c=(p-256)>>1; even->K col c, odd->V col c, scaled x64 (fp8 out)
//   p>=768     : skip col p-768                (bf16 output)
__global__ __launch_bounds__(256) void pack_w_kernel(
    const float* __restrict__ Wq, const float* __restrict__ Wk,
    const float* __restrict__ Wv, const float* __restrict__ Ws,
    const float* __restrict__ bq, const float* __restrict__ bk,
    const float* __restrict__ bv, const float* __restrict__ bs,
    unsigned short* __restrict__ wpack, float* __restrict__ biasF) {
    int t = blockIdx.x * 256 + threadIdx.x;  // 262144 total
    int e = t & 7, lane = (t >> 3) & 63, kk = (t >> 9) & 7, n_tile = t >> 12;
    int k = kk * 32 + (lane >> 4) * 8 + e;
    int p = n_tile * 16 + (lane & 15);
    const float* W[4] = {Wq, Wk, Wv, Ws};
    int mat, col;
    if (p < 256) { mat = 0; col = p; }
    else if (p < 768) { col = (p - 256) >> 1; mat = ((p - 256) & 1) ? 2 : 1; }
    else { mat = 3; col = p - 768; }
    float scale = (mat == 1 || mat == 2) ? 64.0f : 1.0f;
    wpack[t] = f2bf(W[mat][k * 256 + col] * scale);
    if (t < 1024) {
        const float* B[4] = {bq, bk, bv, bs};
        int p2 = t, mat2, col2;
        if (p2 < 256) { mat2 = 0; col2 = p2; }
        else if (p2 < 768) { col2 = (p2 - 256) >> 1; mat2 = ((p2 - 256) & 1) ? 2 : 1; }
        else { mat2 = 3; col2 = p2 - 768; }
        float s2 = (mat2 == 1 || mat2 == 2) ? 64.0f : 1.0f;
        biasF[t] = B[mat2][col2] * s2;
    }
}

// ---------------- CSR build ----------------
__global__ __launch_bounds__(256) void hist_kernel(
    const int* __restrict__ dst, int* __restrict__ deg, int ne) {
    int e = blockIdx.x * 256 + threadIdx.x;
    if (e < ne) atomicAdd(&deg[dst[e]], 1);
}

// wave-chunked coalesced scan: 16 waves x 3200-elem chunks; provisional
// within-chunk exclusive prefix to row_ptr; per-wave offsets to woff[16].
__global__ __launch_bounds__(1024) void scan_kernel(
    const int* __restrict__ deg, int* __restrict__ row_ptr,
    int* __restrict__ woff, int n) {
    const int CHUNK = 3200;  // 16*3200 = 51200 >= 50001
    int tid = threadIdx.x, lane = tid & 63, wv = tid >> 6;
    int base = wv * CHUNK;
    int carry = 0;
    for (int k = 0; k < CHUNK; k += 64) {
        int idx = base + k + lane;
        int v = (idx < n) ? deg[idx] : 0;
        int inc = v;
#pragma unroll
        for (int off = 1; off < 64; off <<= 1) {
            int t2 = __shfl_up(inc, off);
            if (lane >= off) inc += t2;
        }
        if (idx < n) row_ptr[idx] = carry + inc - v;  // provisional exclusive
        carry += __shfl(inc, 63);
    }
    __shared__ int sTot[16];
    if (lane == 0) sTot[wv] = carry;
    if (tid == 1023) row_ptr[n] = carry;  // provisional; fixup adds woff[15]
    __syncthreads();
    if (tid < 16) {
        int v = sTot[tid], in2 = v;
        for (int off = 1; off < 16; off <<= 1) {
            int t2 = __shfl_up(in2, off);
            if (tid >= off) in2 += t2;
        }
        woff[tid] = in2 - v;  // exclusive wave offset
    }
}

__global__ __launch_bounds__(256) void fixup_kernel(
    int* __restrict__ row_ptr, int* __restrict__ fill,
    const int* __restrict__ woff, int n) {
    int idx = blockIdx.x * 256 + threadIdx.x;
    if (idx > n) return;
    int v = row_ptr[idx] + woff[idx / 3200];
    row_ptr[idx] = v;
    if (idx < n) fill[idx] = v;
}

__global__ __launch_bounds__(256) void scatter_kernel(
    const int* __restrict__ src, const int* __restrict__ dst,
    int* __restrict__ fill, int* __restrict__ csr_src, int ne) {
    int e = blockIdx.x * 256 + threadIdx.x;
    if (e < ne) {
        int pos = atomicAdd(&fill[dst[e]], 1);
        csr_src[pos] = src[e];
    }
}

// ---------------- fused QKVS GEMM (bf16 MFMA, no LDS) ----------------
// Output row (1536 B): [0,512) q bf16 | [512,1024) kv fp8 (k0 v0 k1 v1 ...) |
// [1024,1536) skip bf16.  XCD-chunked 1D grid.
__global__ __launch_bounds__(256) void gemm_kernel(
    const unsigned short* __restrict__ xb,     // [N][256] bf16
    const unsigned short* __restrict__ wpack,  // packed B
    const float* __restrict__ biasF,           // [1024]
    unsigned char* __restrict__ qkvs,          // [N][1536 B]
    int n_nodes) {
    int bid = blockIdx.x;                      // 6256 = 8 * 782
    int work = (bid & 7) * 782 + (bid >> 3);
    int mt = work >> 4;
    int nt = work & 15;
    int lane = threadIdx.x & 63;
    int wv = threadIdx.x >> 6;
    int row_w = mt * 128 + wv * 32;
    int n0 = nt * 64;

    f32x4 acc[2][4];
#pragma unroll
    for (int mi = 0; mi < 2; ++mi)
#pragma unroll
        for (int ni = 0; ni < 4; ++ni) {
            f32x4 z = {0.f, 0.f, 0.f, 0.f};
            acc[mi][ni] = z;
        }

    int arow0 = min(row_w + (lane & 15), n_nodes - 1);
    int arow1 = min(row_w + 16 + (lane & 15), n_nodes - 1);
    int acol = (lane >> 4) * 8;
    const uint4* bbase = reinterpret_cast<const uint4*>(wpack);
    int ntile0 = n0 >> 4;

#pragma unroll
    for (int kk = 0; kk < 8; ++kk) {
        bf16x8 a[2], b[4];
        {
            uint4 u0 = *reinterpret_cast<const uint4*>(xb + (size_t)arow0 * 256 + kk * 32 + acol);
            uint4 u1 = *reinterpret_cast<const uint4*>(xb + (size_t)arow1 * 256 + kk * 32 + acol);
            a[0] = __builtin_bit_cast(bf16x8, u0);
            a[1] = __builtin_bit_cast(bf16x8, u1);
        }
#pragma unroll
        for (int ni = 0; ni < 4; ++ni) {
            uint4 u = bbase[((size_t)(ntile0 + ni) * 8 + kk) * 64 + lane];
            b[ni] = __builtin_bit_cast(bf16x8, u);
        }
#pragma unroll
        for (int mi = 0; mi < 2; ++mi)
#pragma unroll
            for (int ni = 0; ni < 4; ++ni)
                acc[mi][ni] = __builtin_amdgcn_mfma_f32_16x16x32_bf16(a[mi], b[ni], acc[mi][ni], 0, 0, 0);
    }

    int region = (n0 < 256) ? 0 : (n0 < 768 ? 1 : 2);
#pragma unroll
    for (int mi = 0; mi < 2; ++mi) {
        int rbase = row_w + mi * 16 + (lane >> 4) * 4;
#pragma unroll
        for (int ni = 0; ni < 4; ++ni) {
            int col = n0 + ni * 16 + (lane & 15);
            float bias = biasF[col];
#pragma unroll
            for (int r = 0; r < 4; ++r) {
                int row = rbase + r;
                if (row < n_nodes) {
                    float val = acc[mi][ni][r] + bias;
                    size_t rb = (size_t)row * 1536;
                    if (region == 0) {
                        *reinterpret_cast<unsigned short*>(qkvs + rb + col * 2) = f2bf(val);
                    } else if (region == 1) {
                        int p8 = __builtin_amdgcn_cvt_pk_fp8_f32(val, val, 0, false);
                        qkvs[rb + 512 + (col - 256)] = (unsigned char)(p8 & 0xff);
                    } else {
                        *reinterpret_cast<unsigned short*>(qkvs + rb + 1024 + (col - 768) * 2) = f2bf(val);
                    }
                }
            }
        }
    }
}

// ---------------- fused edge aggregation + epilogue ----------------
// 1 block per dst node; 4 waves; each wave = 2 edges (2 x 32 lanes x 8 ch).
__global__ __launch_bounds__(256) void edge_agg_kernel(
    const int* __restrict__ row_ptr, const int* __restrict__ csr_src,
    const unsigned char* __restrict__ qkvs, const unsigned short* __restrict__ xb,
    const float* __restrict__ gamma, const float* __restrict__ beta,
    float* __restrict__ out) {
    int i = blockIdx.x;
    int t = threadIdx.x;
    int wv = t >> 6, lane = t & 63, half = lane >> 5, l = lane & 31;
    int slot = wv * 2 + half;  // 0..7 edge slots

    // q channels c0 = l*8 .. +7; prescale by log2(e)/sqrt(32)/64 (K stored x64)
    const float QS = 0.17677669529663687f * 1.4426950408889634f / 64.0f;
    const unsigned char* rowi = qkvs + (size_t)i * 1536;
    uint4 qu = *reinterpret_cast<const uint4*>(rowi + l * 16);
    float q0 = __uint_as_float(qu.x << 16) * QS;
    float q1 = __uint_as_float(qu.x & 0xffff0000u) * QS;
    float q2 = __uint_as_float(qu.y << 16) * QS;
    float q3 = __uint_as_float(qu.y & 0xffff0000u) * QS;
    float q4 = __uint_as_float(qu.z << 16) * QS;
    float q5 = __uint_as_float(qu.z & 0xffff0000u) * QS;
    float q6 = __uint_as_float(qu.w << 16) * QS;
    float q7 = __uint_as_float(qu.w & 0xffff0000u) * QS;

    int e0 = row_ptr[i], e1 = row_ptr[i + 1];
    float a0 = 0.f, a1 = 0.f, a2 = 0.f, a3 = 0.f;
    float a4 = 0.f, a5 = 0.f, a6 = 0.f, a7 = 0.f, den = 0.f;
    int e = e0 + slot;
    int j = (e < e1) ? csr_src[e] : 0;
    for (; e < e1; e += 8) {
        int jn = (e + 8 < e1) ? csr_src[e + 8] : 0;
        uint4 u = *reinterpret_cast<const uint4*>(qkvs + (size_t)j * 1536 + 512 + l * 16);
        f32x2 p0 = __builtin_amdgcn_cvt_pk_f32_fp8(u.x, false);
        f32x2 p1 = __builtin_amdgcn_cvt_pk_f32_fp8(u.x, true);
        f32x2 p2 = __builtin_amdgcn_cvt_pk_f32_fp8(u.y, false);
        f32x2 p3 = __builtin_amdgcn_cvt_pk_f32_fp8(u.y, true);
        f32x2 p4 = __builtin_amdgcn_cvt_pk_f32_fp8(u.z, false);
        f32x2 p5 = __builtin_amdgcn_cvt_pk_f32_fp8(u.z, true);
        f32x2 p6 = __builtin_amdgcn_cvt_pk_f32_fp8(u.w, false);
        f32x2 p7 = __builtin_amdgcn_cvt_pk_f32_fp8(u.w, true);
        float s = q0 * p0[0];
        s = fmaf(q1, p1[0], s);
        s = fmaf(q2, p2[0], s);
        s = fmaf(q3, p3[0], s);
        s = fmaf(q4, p4[0], s);
        s = fmaf(q5, p5[0], s);
        s = fmaf(q6, p6[0], s);
        s = fmaf(q7, p7[0], s);
        s += __shfl_xor(s, 1);
        s += __shfl_xor(s, 2);   // head dot = 4 lanes; logits tiny, no max shift
        float w = exp2f(s);
        den += w;
        a0 = fmaf(w, p0[1], a0);
        a1 = fmaf(w, p1[1], a1);
        a2 = fmaf(w, p2[1], a2);
        a3 = fmaf(w, p3[1], a3);
        a4 = fmaf(w, p4[1], a4);
        a5 = fmaf(w, p5[1], a5);
        a6 = fmaf(w, p6[1], a6);
        a7 = fmaf(w, p7[1], a7);
        j = jn;
    }

    __shared__ float sAcc[4][64][8];
    __shared__ float sDen[4][2][8];
    sAcc[wv][lane][0] = a0; sAcc[wv][lane][1] = a1;
    sAcc[wv][lane][2] = a2; sAcc[wv][lane][3] = a3;
    sAcc[wv][lane][4] = a4; sAcc[wv][lane][5] = a5;
    sAcc[wv][lane][6] = a6; sAcc[wv][lane][7] = a7;
    if ((l & 3) == 0) sDen[wv][half][l >> 2] = den;
    __syncthreads();

    // epilogue: thread t = channel c
    int c = t, lc = c >> 3, m = c & 7, h = c >> 5;
    float acc = 0.f, d = 0.f;
#pragma unroll
    for (int w2 = 0; w2 < 4; ++w2) {
        acc += sAcc[w2][lc][m] + sAcc[w2][32 + lc][m];
        d += sDen[w2][0][h] + sDen[w2][1][h];
    }
    float agg = (d > 0.f) ? acc / (d * 64.0f) : 0.f;  // 1/64 undoes V scale

    float pre = agg + bf2f(*reinterpret_cast<const unsigned short*>(rowi + 1024 + c * 2));
    float gel = 0.5f * pre * (1.f + erff(pre * 0.70710678118654752f));
    float y = bf2f(xb[(size_t)i * 256 + c]) + gel;

    float s1 = y, s2 = y * y;
#pragma unroll
    for (int mm = 1; mm <= 32; mm <<= 1) {
        s1 += __shfl_xor(s1, mm);
        s2 += __shfl_xor(s2, mm);
    }
    __shared__ float red[8];
    int ln = t & 63;
    if (ln == 0) { red[wv] = s1; red[4 + wv] = s2; }
    __syncthreads();
    float sum = red[0] + red[1] + red[2] + red[3];
    float ssq = red[4] + red[5] + red[6] + red[7];
    float mu = sum * (1.f / 256.f);
    float var = ssq * (1.f / 256.f) - mu * mu;
    float rstd = rsqrtf(var + 1e-5f);
    out[(size_t)i * 256 + c] = (y - mu) * rstd * gamma[c] + beta[c];
}

extern "C" void kernel_launch(void* const* d_in, const int* in_sizes, int n_in,
                              void* d_out, int out_size, void* d_ws, size_t ws_size,
                              hipStream_t stream) {
    const float* x    = (const float*)d_in[0];
    const int*   ei   = (const int*)d_in[1];
    const float* Wq   = (const float*)d_in[2];
    const float* bq   = (const float*)d_in[3];
    const float* Wk   = (const float*)d_in[4];
    const float* bk   = (const float*)d_in[5];
    const float* Wv   = (const float*)d_in[6];
    const float* bv   = (const float*)d_in[7];
    const float* Wsk  = (const float*)d_in[8];
    const float* bsk  = (const float*)d_in[9];
    const float* gamma = (const float*)d_in[10];
    const float* beta  = (const float*)d_in[11];
    const int* src = ei;
    const int* dst = ei + N_EDGES;

    char* ws = (char*)d_ws;
    size_t off = 0;
    auto alloc = [&](size_t bytes) -> void* {
        void* p = ws + off;
        off += (bytes + 255) & ~(size_t)255;
        return p;
    };
    unsigned short* xb     = (unsigned short*)alloc((size_t)N_NODES * 256 * 2);
    unsigned char*  qkvs   = (unsigned char*)alloc((size_t)N_NODES * 1536);
    unsigned short* wpack  = (unsigned short*)alloc(262144 * 2);
    float*          biasF  = (float*)alloc(1024 * 4);
    int*            deg    = (int*)alloc((size_t)N_NODES * 4);
    int*            rowp   = (int*)alloc((size_t)(N_NODES + 1) * 4);
    int*            fill   = (int*)alloc((size_t)N_NODES * 4);
    int*            csr    = (int*)alloc((size_t)N_EDGES * 4);
    int*            woff   = (int*)alloc(64);
    (void)ws_size;

    hipMemsetAsync(deg, 0, (size_t)N_NODES * 4, stream);
    convert_x_kernel<<<(N_NODES * 256 / 8 + 255) / 256, 256, 0, stream>>>(
        x, xb, N_NODES * 256 / 8);
    pack_w_kernel<<<1024, 256, 0, stream>>>(Wq, Wk, Wv, Wsk, bq, bk, bv, bsk, wpack, biasF);
    hist_kernel<<<(N_EDGES + 255) / 256, 256, 0, stream>>>(dst, deg, N_EDGES);
    scan_kernel<<<1, 1024, 0, stream>>>(deg, rowp, woff, N_NODES);
    fixup_kernel<<<196, 256, 0, stream>>>(rowp, fill, woff, N_NODES);
    scatter_kernel<<<(N_EDGES + 255) / 256, 256, 0, stream>>>(src, dst, fill, csr, N_EDGES);
    gemm_kernel<<<6256, 256, 0, stream>>>(xb, wpack, biasF, qkvs, N_NODES);
    edge_agg_kernel<<<N_NODES, 256, 0, stream>>>(rowp, csr, qkvs, xb, gamma, beta, (float*)d_out);
}

// Round 4
// 265.921 us; speedup vs baseline: 2.1974x; 1.2535x over previous
//
#include <hip/hip_runtime.h>

#define N_NODES 50000
#define HID 256
#define HEADS 8
#define HDIM 32
#define N_EDGES 800000

typedef __bf16 bf16x8 __attribute__((ext_vector_type(8)));
typedef float f32x4 __attribute__((ext_vector_type(4)));
typedef float f32x2 __attribute__((ext_vector_type(2)));

__device__ __forceinline__ unsigned short f2bf(float f) {
    unsigned int b = __float_as_uint(f);
    unsigned int r = (b + 0x7FFFu + ((b >> 16) & 1u)) >> 16;
    return (unsigned short)r;
}
__device__ __forceinline__ float bf2f(unsigned short u) {
    return __uint_as_float(((unsigned int)u) << 16);
}
__device__ __forceinline__ f32x2 bfpair(unsigned int u) {
    f32x2 r;
    r[0] = __uint_as_float(u << 16);
    r[1] = __uint_as_float(u & 0xffff0000u);
    return r;
}

// ---------------- fused convert (x fp32->bf16) + degree histogram ----------------
// blocks [0,6250): convert (6250*256 = 1.6M uint4-groups = 50000*256/8)
// blocks [6250,9375): hist (3125*256 = 800000 edges)
__global__ __launch_bounds__(256) void prep_kernel(
    const float* __restrict__ x, unsigned short* __restrict__ xb,
    const int* __restrict__ dst, int* __restrict__ deg) {
    int b = blockIdx.x;
    if (b < 6250) {
        int t = b * 256 + threadIdx.x;
        const float4* p = reinterpret_cast<const float4*>(x) + (size_t)t * 2;
        float4 f0 = p[0], f1 = p[1];
        uint4 o;
        o.x = (unsigned)f2bf(f0.x) | ((unsigned)f2bf(f0.y) << 16);
        o.y = (unsigned)f2bf(f0.z) | ((unsigned)f2bf(f0.w) << 16);
        o.z = (unsigned)f2bf(f1.x) | ((unsigned)f2bf(f1.y) << 16);
        o.w = (unsigned)f2bf(f1.z) | ((unsigned)f2bf(f1.w) << 16);
        reinterpret_cast<uint4*>(xb)[t] = o;
    } else {
        int e = (b - 6250) * 256 + threadIdx.x;
        atomicAdd(&deg[dst[e]], 1);
    }
}

// ---------------- pack fused weights into MFMA B-fragment order ----------------
// Fused column p in [0,1024):
//   p<256      : Q col p (bf16 out)
//   256<=p<768 : p'=p-256; quad=p'>>2, r=p'&3: r<2 -> K ch quad*2+r,
//                r>=2 -> V ch quad*2+(r-2); scaled x64 (fp8 out, kkvv quads)
//   p>=768     : skip col p-768 (bf16 out)
__device__ __forceinline__ void fused_col_map(int p, int& mat, int& col, float& scale) {
    if (p < 256) { mat = 0; col = p; scale = 1.0f; }
    else if (p < 768) {
        int pp = p - 256;
        mat = ((pp & 2) ? 2 : 1);
        col = ((pp >> 2) << 1) | (pp & 1);
        scale = 64.0f;
    } else { mat = 3; col = p - 768; scale = 1.0f; }
}

__global__ __launch_bounds__(256) void pack_w_kernel(
    const float* __restrict__ Wq, const float* __restrict__ Wk,
    const float* __restrict__ Wv, const float* __restrict__ Ws,
    const float* __restrict__ bq, const float* __restrict__ bk,
    const float* __restrict__ bv, const float* __restrict__ bs,
    unsigned short* __restrict__ wpack, float* __restrict__ biasF) {
    int t = blockIdx.x * 256 + threadIdx.x;  // 262144 total
    int e = t & 7, lane = (t >> 3) & 63, kk = (t >> 9) & 7, n_tile = t >> 12;
    int k = kk * 32 + (lane >> 4) * 8 + e;
    int p = n_tile * 16 + (lane & 15);
    const float* W[4] = {Wq, Wk, Wv, Ws};
    int mat, col; float scale;
    fused_col_map(p, mat, col, scale);
    wpack[t] = f2bf(W[mat][k * 256 + col] * scale);
    if (t < 1024) {
        const float* B[4] = {bq, bk, bv, bs};
        int mat2, col2; float s2;
        fused_col_map(t, mat2, col2, s2);
        biasF[t] = B[mat2][col2] * s2;
    }
}

// ---------------- CSR build: parallel scan ----------------
// scan1: 50 blocks x 1024 thr, chunk=1024; provisional prefixes + block totals
__global__ __launch_bounds__(1024) void scan1_kernel(
    const int* __restrict__ deg, int* __restrict__ row_ptr,
    int* __restrict__ btot, int n) {
    int tid = threadIdx.x, lane = tid & 63, wv = tid >> 6;
    int idx = blockIdx.x * 1024 + tid;
    int v = (idx < n) ? deg[idx] : 0;
    int inc = v;
#pragma unroll
    for (int off = 1; off < 64; off <<= 1) {
        int t2 = __shfl_up(inc, off);
        if (lane >= off) inc += t2;
    }
    __shared__ int sW[16], sO[16];
    if (lane == 63) sW[wv] = inc;
    __syncthreads();
    if (tid < 16) {
        int vv = sW[tid], in2 = vv;
        for (int off = 1; off < 16; off <<= 1) {
            int t2 = __shfl_up(in2, off);
            if (tid >= off) in2 += t2;
        }
        sO[tid] = in2 - vv;
    }
    __syncthreads();
    int excl = sO[wv] + inc - v;
    if (idx <= n) row_ptr[idx] = excl;  // provisional
    if (tid == 1023) btot[blockIdx.x] = excl + v;
}

__global__ __launch_bounds__(64) void scan2_kernel(
    const int* __restrict__ btot, int* __restrict__ boff, int nb) {
    int t = threadIdx.x;
    int v = (t < nb) ? btot[t] : 0;
    int inc = v;
#pragma unroll
    for (int off = 1; off < 64; off <<= 1) {
        int t2 = __shfl_up(inc, off);
        if (t >= off) inc += t2;
    }
    if (t < nb) boff[t] = inc - v;
}

__global__ __launch_bounds__(256) void fixup_kernel(
    int* __restrict__ row_ptr, int* __restrict__ fill,
    const int* __restrict__ boff, int n) {
    int idx = blockIdx.x * 256 + threadIdx.x;
    if (idx > n) return;
    int v = row_ptr[idx] + boff[idx >> 10];
    row_ptr[idx] = v;
    if (idx < n) fill[idx] = v;
}

__global__ __launch_bounds__(256) void scatter_kernel(
    const int* __restrict__ src, const int* __restrict__ dst,
    int* __restrict__ fill, int* __restrict__ csr_src, int ne) {
    int e = blockIdx.x * 256 + threadIdx.x;
    if (e < ne) {
        int pos = atomicAdd(&fill[dst[e]], 1);
        csr_src[pos] = src[e];
    }
}

// ---------------- fused QKVS GEMM (bf16 MFMA, no LDS) ----------------
// Output row (1536 B): [0,512) q bf16 | [512,1024) kv fp8 kkvv-quads |
// [1024,1536) skip bf16.  XCD-chunked 1D grid.
__global__ __launch_bounds__(256) void gemm_kernel(
    const unsigned short* __restrict__ xb,     // [N][256] bf16
    const unsigned short* __restrict__ wpack,  // packed B
    const float* __restrict__ biasF,           // [1024]
    unsigned char* __restrict__ qkvs,          // [N][1536 B]
    int n_nodes) {
    int bid = blockIdx.x;                      // 6256 = 8 * 782
    int work = (bid & 7) * 782 + (bid >> 3);
    int mt = work >> 4;
    int nt = work & 15;
    int lane = threadIdx.x & 63;
    int wv = threadIdx.x >> 6;
    int row_w = mt * 128 + wv * 32;
    int n0 = nt * 64;

    f32x4 acc[2][4];
#pragma unroll
    for (int mi = 0; mi < 2; ++mi)
#pragma unroll
        for (int ni = 0; ni < 4; ++ni) {
            f32x4 z = {0.f, 0.f, 0.f, 0.f};
            acc[mi][ni] = z;
        }

    int arow0 = min(row_w + (lane & 15), n_nodes - 1);
    int arow1 = min(row_w + 16 + (lane & 15), n_nodes - 1);
    int acol = (lane >> 4) * 8;
    const uint4* bbase = reinterpret_cast<const uint4*>(wpack);
    int ntile0 = n0 >> 4;

#pragma unroll
    for (int kk = 0; kk < 8; ++kk) {
        bf16x8 a[2], b[4];
        {
            uint4 u0 = *reinterpret_cast<const uint4*>(xb + (size_t)arow0 * 256 + kk * 32 + acol);
            uint4 u1 = *reinterpret_cast<const uint4*>(xb + (size_t)arow1 * 256 + kk * 32 + acol);
            a[0] = __builtin_bit_cast(bf16x8, u0);
            a[1] = __builtin_bit_cast(bf16x8, u1);
        }
#pragma unroll
        for (int ni = 0; ni < 4; ++ni) {
            uint4 u = bbase[((size_t)(ntile0 + ni) * 8 + kk) * 64 + lane];
            b[ni] = __builtin_bit_cast(bf16x8, u);
        }
#pragma unroll
        for (int mi = 0; mi < 2; ++mi)
#pragma unroll
            for (int ni = 0; ni < 4; ++ni)
                acc[mi][ni] = __builtin_amdgcn_mfma_f32_16x16x32_bf16(a[mi], b[ni], acc[mi][ni], 0, 0, 0);
    }

    int region = (n0 < 256) ? 0 : (n0 < 768 ? 1 : 2);
#pragma unroll
    for (int mi = 0; mi < 2; ++mi) {
        int rbase = row_w + mi * 16 + (lane >> 4) * 4;
#pragma unroll
        for (int ni = 0; ni < 4; ++ni) {
            int col = n0 + ni * 16 + (lane & 15);
            float bias = biasF[col];
#pragma unroll
            for (int r = 0; r < 4; ++r) {
                int row = rbase + r;
                if (row < n_nodes) {
                    float val = acc[mi][ni][r] + bias;
                    size_t rb = (size_t)row * 1536;
                    if (region == 0) {
                        *reinterpret_cast<unsigned short*>(qkvs + rb + col * 2) = f2bf(val);
                    } else if (region == 1) {
                        int p8 = __builtin_amdgcn_cvt_pk_fp8_f32(val, val, 0, false);
                        qkvs[rb + 512 + (col - 256)] = (unsigned char)(p8 & 0xff);
                    } else {
                        *reinterpret_cast<unsigned short*>(qkvs + rb + 1024 + (col - 768) * 2) = f2bf(val);
                    }
                }
            }
        }
    }
}

// ---------------- fused edge aggregation + epilogue: 1 wave = 1 node ----------------
// block = 256 thr = 4 independent nodes. Per wave: 2 edges/iter
// (half = lane>>5 picks edge, l = lane&31 covers 8 channels = l*8..l*8+7).
// No LDS, no barriers. Cross-half combine + LN reduce via shuffles only.
__global__ __launch_bounds__(256) void edge_agg_kernel(
    const int* __restrict__ row_ptr, const int* __restrict__ csr_src,
    const unsigned char* __restrict__ qkvs, const unsigned short* __restrict__ xb,
    const float* __restrict__ gamma, const float* __restrict__ beta,
    float* __restrict__ out) {
    int wv = threadIdx.x >> 6;
    int i = blockIdx.x * 4 + wv;          // 12500*4 = 50000 exact
    int lane = threadIdx.x & 63;
    int half = lane >> 5, l = lane & 31;

    // q channels l*8..+7, prescaled by log2(e)/sqrt(32)/64 (K stored x64)
    const float QS = 0.17677669529663687f * 1.4426950408889634f / 64.0f;
    const unsigned char* rowi = qkvs + (unsigned)i * 1536u;
    uint4 qu = *reinterpret_cast<const uint4*>(rowi + l * 16);
    f32x2 qsc = {QS, QS};
    f32x2 q01 = bfpair(qu.x) * qsc;
    f32x2 q23 = bfpair(qu.y) * qsc;
    f32x2 q45 = bfpair(qu.z) * qsc;
    f32x2 q67 = bfpair(qu.w) * qsc;

    int e0 = row_ptr[i], e1 = row_ptr[i + 1];
    f32x2 acc0 = {0.f, 0.f}, acc1 = {0.f, 0.f}, acc2 = {0.f, 0.f}, acc3 = {0.f, 0.f};
    float den = 0.f;
    int e = e0 + half;
    int j = (e < e1) ? csr_src[e] : 0;
    while (e < e1) {
        int jn = (e + 2 < e1) ? csr_src[e + 2] : 0;
        uint4 u = *reinterpret_cast<const uint4*>(
            qkvs + (unsigned)j * 1536u + 512u + (unsigned)l * 16u);
        f32x2 k01 = __builtin_amdgcn_cvt_pk_f32_fp8(u.x, false);
        f32x2 v01 = __builtin_amdgcn_cvt_pk_f32_fp8(u.x, true);
        f32x2 k23 = __builtin_amdgcn_cvt_pk_f32_fp8(u.y, false);
        f32x2 v23 = __builtin_amdgcn_cvt_pk_f32_fp8(u.y, true);
        f32x2 k45 = __builtin_amdgcn_cvt_pk_f32_fp8(u.z, false);
        f32x2 v45 = __builtin_amdgcn_cvt_pk_f32_fp8(u.z, true);
        f32x2 k67 = __builtin_amdgcn_cvt_pk_f32_fp8(u.w, false);
        f32x2 v67 = __builtin_amdgcn_cvt_pk_f32_fp8(u.w, true);
        f32x2 d = q01 * k01;
        d = __builtin_elementwise_fma(q23, k23, d);
        d = __builtin_elementwise_fma(q45, k45, d);
        d = __builtin_elementwise_fma(q67, k67, d);
        float s = d[0] + d[1];
        s += __shfl_xor(s, 1);
        s += __shfl_xor(s, 2);   // head dot = 4 lanes; logits tiny, no max shift
        float w = exp2f(s);
        den += w;
        f32x2 w2 = {w, w};
        acc0 = __builtin_elementwise_fma(w2, v01, acc0);
        acc1 = __builtin_elementwise_fma(w2, v23, acc1);
        acc2 = __builtin_elementwise_fma(w2, v45, acc2);
        acc3 = __builtin_elementwise_fma(w2, v67, acc3);
        j = jn;
        e += 2;
    }

    // combine the two edge-halves (channels identical across halves)
    acc0[0] += __shfl_xor(acc0[0], 32); acc0[1] += __shfl_xor(acc0[1], 32);
    acc1[0] += __shfl_xor(acc1[0], 32); acc1[1] += __shfl_xor(acc1[1], 32);
    acc2[0] += __shfl_xor(acc2[0], 32); acc2[1] += __shfl_xor(acc2[1], 32);
    acc3[0] += __shfl_xor(acc3[0], 32); acc3[1] += __shfl_xor(acc3[1], 32);
    den += __shfl_xor(den, 32);
    float inv = (den > 0.f) ? 1.0f / (den * 64.0f) : 0.f;  // undo V x64

    // epilogue: skip + tanh-GELU (sigmoid form) + residual, per-lane 8 channels
    uint4 su = *reinterpret_cast<const uint4*>(rowi + 1024 + l * 16);
    uint4 xu = *reinterpret_cast<const uint4*>(
        reinterpret_cast<const unsigned char*>(xb) + (unsigned)i * 512u + l * 16);
    const float C1 = -2.3022650556f;          // -2*log2(e)*0.7978845608
    const float C2 = -0.10294578f;            // C1*0.044715
    float s1 = 0.f, s2 = 0.f;
    f32x2 y01, y23, y45, y67;
#define GNN_PROC(A, SRAW, XRAW, Y)                                   \
    {                                                                \
        f32x2 sk = bfpair(SRAW), xr = bfpair(XRAW);                  \
        _Pragma("unroll")                                            \
        for (int qq = 0; qq < 2; ++qq) {                             \
            float pre = fmaf(A[qq], inv, sk[qq]);                    \
            float x2 = pre * pre;                                    \
            float arg = pre * fmaf(C2, x2, C1);                      \
            float gel = pre / (1.f + exp2f(arg));                    \
            float yy = xr[qq] + gel;                                 \
            Y[qq] = yy;                                              \
            s1 += yy;                                                \
            s2 = fmaf(yy, yy, s2);                                   \
        }                                                            \
    }
    GNN_PROC(acc0, su.x, xu.x, y01)
    GNN_PROC(acc1, su.y, xu.y, y23)
    GNN_PROC(acc2, su.z, xu.z, y45)
    GNN_PROC(acc3, su.w, xu.w, y67)
#undef GNN_PROC

    // LN reduce: each 32-lane half covers all 256 channels -> xor 1..16 suffices
#pragma unroll
    for (int m = 1; m <= 16; m <<= 1) {
        s1 += __shfl_xor(s1, m);
        s2 += __shfl_xor(s2, m);
    }
    float mu = s1 * (1.f / 256.f);
    float var = s2 * (1.f / 256.f) - mu * mu;
    float rstd = rsqrtf(var + 1e-5f);

    if (half == 0) {
        const float4* g4 = reinterpret_cast<const float4*>(gamma) + l * 2;
        const float4* b4 = reinterpret_cast<const float4*>(beta) + l * 2;
        float4 ga = g4[0], gb = g4[1], ba = b4[0], bb = b4[1];
        float4 o0, o1;
        o0.x = (y01[0] - mu) * rstd * ga.x + ba.x;
        o0.y = (y01[1] - mu) * rstd * ga.y + ba.y;
        o0.z = (y23[0] - mu) * rstd * ga.z + ba.z;
        o0.w = (y23[1] - mu) * rstd * ga.w + ba.w;
        o1.x = (y45[0] - mu) * rstd * gb.x + bb.x;
        o1.y = (y45[1] - mu) * rstd * gb.y + bb.y;
        o1.z = (y67[0] - mu) * rstd * gb.z + bb.z;
        o1.w = (y67[1] - mu) * rstd * gb.w + bb.w;
        float4* op = reinterpret_cast<float4*>(out + (unsigned)i * 256u + l * 8);
        op[0] = o0;
        op[1] = o1;
    }
}

extern "C" void kernel_launch(void* const* d_in, const int* in_sizes, int n_in,
                              void* d_out, int out_size, void* d_ws, size_t ws_size,
                              hipStream_t stream) {
    const float* x    = (const float*)d_in[0];
    const int*   ei   = (const int*)d_in[1];
    const float* Wq   = (const float*)d_in[2];
    const float* bq   = (const float*)d_in[3];
    const float* Wk   = (const float*)d_in[4];
    const float* bk   = (const float*)d_in[5];
    const float* Wv   = (const float*)d_in[6];
    const float* bv   = (const float*)d_in[7];
    const float* Wsk  = (const float*)d_in[8];
    const float* bsk  = (const float*)d_in[9];
    const float* gamma = (const float*)d_in[10];
    const float* beta  = (const float*)d_in[11];
    const int* src = ei;
    const int* dst = ei + N_EDGES;

    char* ws = (char*)d_ws;
    size_t off = 0;
    auto alloc = [&](size_t bytes) -> void* {
        void* p = ws + off;
        off += (bytes + 255) & ~(size_t)255;
        return p;
    };
    unsigned short* xb     = (unsigned short*)alloc((size_t)N_NODES * 256 * 2);
    unsigned char*  qkvs   = (unsigned char*)alloc((size_t)N_NODES * 1536);
    unsigned short* wpack  = (unsigned short*)alloc(262144 * 2);
    float*          biasF  = (float*)alloc(1024 * 4);
    int*            deg    = (int*)alloc((size_t)N_NODES * 4);
    int*            rowp   = (int*)alloc((size_t)(N_NODES + 1) * 4);
    int*            fill   = (int*)alloc((size_t)N_NODES * 4);
    int*            csr    = (int*)alloc((size_t)N_EDGES * 4);
    int*            btot   = (int*)alloc(64 * 4);
    int*            boff   = (int*)alloc(64 * 4);
    (void)ws_size;

    hipMemsetAsync(deg, 0, (size_t)N_NODES * 4, stream);
    prep_kernel<<<9375, 256, 0, stream>>>(x, xb, dst, deg);
    pack_w_kernel<<<1024, 256, 0, stream>>>(Wq, Wk, Wv, Wsk, bq, bk, bv, bsk, wpack, biasF);
    scan1_kernel<<<50, 1024, 0, stream>>>(deg, rowp, btot, N_NODES);
    scan2_kernel<<<1, 64, 0, stream>>>(btot, boff, 50);
    fixup_kernel<<<196, 256, 0, stream>>>(rowp, fill, boff, N_NODES);
    scatter_kernel<<<3125, 256, 0, stream>>>(src, dst, fill, csr, N_EDGES);
    gemm_kernel<<<6256, 256, 0, stream>>>(xb, wpack, biasF, qkvs, N_NODES);
    edge_agg_kernel<<<12500, 256, 0, stream>>>(rowp, csr, qkvs, xb, gamma, beta, (float*)d_out);
}